// Round 1
// 180.671 us; speedup vs baseline: 1.0758x; 1.0758x over previous
//
#include <hip/hip_runtime.h>
#include <hip/hip_bf16.h>
#include <math.h>

#define Bt 8
#define Ct 64
#define Ht 128
#define Wt 128
#define Ot 64
#define HWt (Ht*Wt)

typedef __bf16 bf16x8 __attribute__((ext_vector_type(8)));
typedef float  f32x4  __attribute__((ext_vector_type(4)));

// fp32 -> bf16 bits, round-to-nearest-even, integer ops only
__device__ __forceinline__ uint f2bf_bits(float v) {
    uint u = __float_as_uint(v);
    uint lsb = (u >> 16) & 1u;
    return (u + 0x7fffu + lsb) >> 16;
}
__device__ __forceinline__ ushort f2bf(float v) {
    return (ushort)f2bf_bits(v);
}

// ---------------- prep ----------------
// blocks 0..1023: transpose x NCHW fp32 -> xTb NHWC bf16  [b][y][x][c]
//   mapping b = blk&7 so XCD that writes batch b is the XCD that reads it (L2 affinity)
// blocks 1024.. : weight reshapes
__global__ __launch_bounds__(256) void prep_kernel(
    const float* __restrict__ x, const float* __restrict__ w_off,
    const float* __restrict__ w_mask, const float* __restrict__ w_dcn,
    ushort* __restrict__ xTb, ushort* __restrict__ wOffB, ushort* __restrict__ wMainB)
{
    int blk = blockIdx.x;
    int t = threadIdx.x;
    if (blk < 1024) {
        __shared__ float L[64][128];
        int b = blk & 7, y = blk >> 3;
        const float* xb = x + (size_t)b * 1048576 + y * 128;
#pragma unroll
        for (int it = 0; it < 8; ++it) {
            int i = it * 256 + t;
            int c = i >> 5, x4 = i & 31;
            *(float4*)&L[c][x4 * 4] = *(const float4*)&xb[(size_t)c * HWt + x4 * 4];
        }
        __syncthreads();
        int px = t >> 1, half = (t & 1) * 32;
        union { ushort u[32]; uint4 q[4]; } pk;
#pragma unroll
        for (int i = 0; i < 32; ++i) pk.u[i] = f2bf(L[half + i][px]);
        uint4* dst = (uint4*)(xTb + ((size_t)(b * 128 + y) * 128 + px) * 64 + half);
        dst[0] = pk.q[0]; dst[1] = pk.q[1]; dst[2] = pk.q[2]; dst[3] = pk.q[3];
    } else {
        int i = (blk - 1024) * 256 + t;
        if (i < 9 * 32 * 64) {
            int c = i & 63, ch = (i >> 6) & 31, k = i >> 11;
            float v = 0.f;
            if (ch < 18)      v = w_off[(ch * 64 + c) * 9 + k];
            else if (ch < 27) v = w_mask[((ch - 18) * 64 + c) * 9 + k];
            wOffB[i] = f2bf(v);
        } else {
            int j = i - 18432;
            if (j < 9 * 64 * 64) {
                int c = j & 63, o = (j >> 6) & 63, k = j >> 12;
                wMainB[j] = f2bf(w_dcn[(o * 64 + c) * 9 + k]);
            }
        }
    }
}

// ---------------- fused: offset/mask conv -> LDS -> bilinear sample + MFMA ----------------
// block: 512 thr, one (b,y) row of 128 px, 8 waves x M=16.
// phase 1: 27-channel offset conv (N=32, K=576), results -> odm LDS [128][28] f32.
// phase 2: main conv N=64 (4 tiles), K=576, odm read from LDS.
// LDS overlay (38,912 B total):
//   phase1: smem[0..18431]  = wOff 288x64 swizzled (36,864 B)
//   phase2: smem[0..12287]  = wS group 192x64 swizzled (24,576 B)
//           smem[12288..]   = odm floats [128][28]      (14,336 B)
// overlay safe: barrier between last wL read and first odm/wS write.
__global__ __launch_bounds__(512) void dcn_fused_kernel(
    const ushort* __restrict__ xTb, const ushort* __restrict__ wOffB,
    const ushort* __restrict__ wMainB, const float* __restrict__ b_off,
    const float* __restrict__ b_mask, const float* __restrict__ b_dcn,
    float* __restrict__ out)
{
    __shared__ ushort smem[19456];          // 38,912 B
    float* odmF = (float*)&smem[12288];     // 3584 floats, bytes [24576, 38912)

    int t = threadIdx.x;
    int blk = blockIdx.x;
    int b = blk & 7, y = blk >> 3;          // XCD batch affinity
    int wv = t >> 6, ln = t & 63;
    int m = ln & 15, cq = ln >> 4;
    int px = wv * 16 + m;

    const ushort* xbb = xTb + (size_t)b * 1048576;

    // ---------- phase 1: offset/mask conv ----------
    {
        // stage all 9 taps of wOff: 2304 16B-chunks, swizzled
#pragma unroll
        for (int it = 0; it < 5; ++it) {
            int j = it * 512 + t;
            if (j < 2304) {
                int row = j >> 3, gch = j & 7;
                int col = ((gch + row) & 7) * 8;
                *(uint4*)&smem[row * 64 + col] = *(const uint4*)&wOffB[(size_t)row * 64 + gch * 8];
            }
        }
        __syncthreads();

        f32x4 acc0 = {0.f, 0.f, 0.f, 0.f};
        f32x4 acc1 = {0.f, 0.f, 0.f, 0.f};
#pragma unroll
        for (int k = 0; k < 9; ++k) {
            int ky = k / 3, kx = k - ky * 3;
            int yy = y + ky - 1;
            int xx = px + kx - 1;
            bool ok = ((unsigned)yy < 128u) && ((unsigned)xx < 128u);
            const ushort* arow = xbb + ((size_t)((yy << 7) + xx)) * 64;
            bf16x8 afr[2];
#pragma unroll
            for (int ks = 0; ks < 2; ++ks) {
                int c0 = ks * 32 + cq * 8;
                uint4 v = {0u, 0u, 0u, 0u};
                if (ok) v = *(const uint4*)&arow[c0];
                afr[ks] = __builtin_bit_cast(bf16x8, v);
            }
            int br0 = k * 32 + m;
            int br1 = br0 + 16;
#pragma unroll
            for (int ks = 0; ks < 2; ++ks) {
                int gs = ks * 4 + cq;
                bf16x8 b0 = __builtin_bit_cast(bf16x8,
                    *(const uint4*)&smem[br0 * 64 + ((gs + br0) & 7) * 8]);
                bf16x8 b1 = __builtin_bit_cast(bf16x8,
                    *(const uint4*)&smem[br1 * 64 + ((gs + br1) & 7) * 8]);
                acc0 = __builtin_amdgcn_mfma_f32_16x16x32_bf16(afr[ks], b0, acc0, 0, 0, 0);
                acc1 = __builtin_amdgcn_mfma_f32_16x16x32_bf16(afr[ks], b1, acc1, 0, 0, 0);
            }
        }
        __syncthreads();   // all wL reads complete: odm region + wS region may now be written

        // epilogue -> odm LDS.  slots: 0..8 = dy[k], 9..17 = dx[k], 18..26 = mask[k]
        int n = m;
        int pxl = wv * 16 + (cq << 2);
#pragma unroll
        for (int r = 0; r < 4; ++r) {
            int pp = pxl + r;
            odmF[pp * 28 + (n & 1) * 9 + (n >> 1)] = acc0[r] + b_off[n];
            int ch = 16 + n;
            float v1 = acc1[r];
            if (ch < 18) {
                odmF[pp * 28 + (ch & 1) * 9 + (ch >> 1)] = v1 + b_off[ch];
            } else if (ch < 27) {
                float val = v1 + b_mask[ch - 18];
                odmF[pp * 28 + 18 + (ch - 18)] = 1.f / (1.f + __expf(-val));
            }
        }

        // stage main-weight group 0 (disjoint from odm region) while epilogue drains
#pragma unroll
        for (int it = 0; it < 3; ++it) {
            int j = it * 512 + t;
            int row = j >> 3, gch = j & 7;
            *(uint4*)&smem[row * 64 + ((gch + row) & 7) * 8] =
                *(const uint4*)&wMainB[(size_t)row * 64 + gch * 8];
        }
        __syncthreads();   // odm + group-0 weights visible
    }

    // ---------- phase 2: bilinear sample + main MFMA ----------
    f32x4 acc[4];
#pragma unroll
    for (int i = 0; i < 4; ++i) acc[i] = f32x4{0.f, 0.f, 0.f, 0.f};

    float fx = (float)px;
    const float* odmRow = odmF + px * 28;

#pragma unroll
    for (int g = 0; g < 3; ++g) {
        // per-group odm preload (odm region is stable; safe across wS restage)
        float dyk[3], dxk[3], mkk[3];
#pragma unroll
        for (int tl = 0; tl < 3; ++tl) {
            int k = g * 3 + tl;
            dyk[tl] = odmRow[k];
            dxk[tl] = odmRow[9 + k];
            mkk[tl] = odmRow[18 + k];
        }
        if (g > 0) {
            __syncthreads();   // prior group's wS reads done
#pragma unroll
            for (int it = 0; it < 3; ++it) {
                int j = it * 512 + t;
                int row = j >> 3, gch = j & 7;
                *(uint4*)&smem[row * 64 + ((gch + row) & 7) * 8] =
                    *(const uint4*)&wMainB[(size_t)(g * 192 + row) * 64 + gch * 8];
            }
            __syncthreads();
        }

#pragma unroll
        for (int tl = 0; tl < 3; ++tl) {
            int k = g * 3 + tl;
            int ky = k / 3, kx = k - ky * 3;
            float dyv = dyk[tl];
            float dxv = dxk[tl];
            float mkv = mkk[tl];
            float py  = (float)(y + ky - 1) + dyv;
            float pxf = fx + (float)(kx - 1) + dxv;
            float y0f = floorf(py), x0f = floorf(pxf);
            float wy1 = py - y0f, wy0 = 1.f - wy1;
            float wx1 = pxf - x0f, wx0 = 1.f - wx1;
            bool vy0 = (y0f >= 0.f) && (y0f <= 127.f);
            bool vy1 = (y0f >= -1.f) && (y0f <= 126.f);
            bool vx0 = (x0f >= 0.f) && (x0f <= 127.f);
            bool vx1 = (x0f >= -1.f) && (x0f <= 126.f);
            float w00 = (vy0 && vx0) ? wy0 * wx0 * mkv : 0.f;
            float w01 = (vy0 && vx1) ? wy0 * wx1 * mkv : 0.f;
            float w10 = (vy1 && vx0) ? wy1 * wx0 * mkv : 0.f;
            float w11 = (vy1 && vx1) ? wy1 * wx1 * mkv : 0.f;
            int yi0 = (int)y0f, xi0 = (int)x0f;
            int y0c = min(max(yi0, 0), 127),     y1c = min(max(yi0 + 1, 0), 127);
            int x0c = min(max(xi0, 0), 127),     x1c = min(max(xi0 + 1, 0), 127);
            const ushort* p00 = xbb + (size_t)((y0c << 7) + x0c) * 64;
            const ushort* p01 = xbb + (size_t)((y0c << 7) + x1c) * 64;
            const ushort* p10 = xbb + (size_t)((y1c << 7) + x0c) * 64;
            const ushort* p11 = xbb + (size_t)((y1c << 7) + x1c) * 64;

            bf16x8 afr[2];
#pragma unroll
            for (int ks = 0; ks < 2; ++ks) {
                int c0 = ks * 32 + cq * 8;
                union { uint4 q; uint u[4]; } v00, v01, v10, v11, wr;
                v00.q = *(const uint4*)(p00 + c0);
                v01.q = *(const uint4*)(p01 + c0);
                v10.q = *(const uint4*)(p10 + c0);
                v11.q = *(const uint4*)(p11 + c0);
#pragma unroll
                for (int j = 0; j < 4; ++j) {
                    float f00l = __uint_as_float(v00.u[j] << 16);
                    float f00h = __uint_as_float(v00.u[j] & 0xffff0000u);
                    float f01l = __uint_as_float(v01.u[j] << 16);
                    float f01h = __uint_as_float(v01.u[j] & 0xffff0000u);
                    float f10l = __uint_as_float(v10.u[j] << 16);
                    float f10h = __uint_as_float(v10.u[j] & 0xffff0000u);
                    float f11l = __uint_as_float(v11.u[j] << 16);
                    float f11h = __uint_as_float(v11.u[j] & 0xffff0000u);
                    float vl = w00 * f00l;
                    vl = fmaf(w01, f01l, vl); vl = fmaf(w10, f10l, vl); vl = fmaf(w11, f11l, vl);
                    float vh = w00 * f00h;
                    vh = fmaf(w01, f01h, vh); vh = fmaf(w10, f10h, vh); vh = fmaf(w11, f11h, vh);
                    wr.u[j] = (f2bf_bits(vh) << 16) | f2bf_bits(vl);
                }
                afr[ks] = __builtin_bit_cast(bf16x8, wr.q);
            }

#pragma unroll
            for (int ks = 0; ks < 2; ++ks) {
                int chk = ks * 4 + cq;           // 16B channel-chunk index
#pragma unroll
                for (int nt = 0; nt < 4; ++nt) {
                    int brow = tl * 64 + nt * 16 + m;
                    bf16x8 bb = __builtin_bit_cast(bf16x8,
                        *(const uint4*)&smem[brow * 64 + ((chk + brow) & 7) * 8]);
                    acc[nt] = __builtin_amdgcn_mfma_f32_16x16x32_bf16(afr[ks], bb, acc[nt], 0, 0, 0);
                }
            }
        }
    }

    // epilogue: direct coalesced float4 stores from C layout
#pragma unroll
    for (int nt = 0; nt < 4; ++nt) {
        int o = nt * 16 + m;
        float bias = b_dcn[o];
        float4 v;
        v.x = acc[nt][0] + bias;
        v.y = acc[nt][1] + bias;
        v.z = acc[nt][2] + bias;
        v.w = acc[nt][3] + bias;
        float* orow = out + ((size_t)(b * 64 + o) << 14) + (y << 7) + wv * 16 + cq * 4;
        *(float4*)orow = v;
    }
}

extern "C" void kernel_launch(void* const* d_in, const int* in_sizes, int n_in,
                              void* d_out, int out_size, void* d_ws, size_t ws_size,
                              hipStream_t stream) {
    const float* x      = (const float*)d_in[0];
    const float* w_off  = (const float*)d_in[1];
    const float* b_off  = (const float*)d_in[2];
    const float* w_mask = (const float*)d_in[3];
    const float* b_mask = (const float*)d_in[4];
    const float* w_dcn  = (const float*)d_in[5];
    const float* b_dcn  = (const float*)d_in[6];
    float* out = (float*)d_out;

    ushort* xTb    = (ushort*)d_ws;                  // 8.4M bf16
    ushort* wOffB  = xTb + (size_t)Bt * HWt * 64;    // 18432
    ushort* wMainB = wOffB + 18432;                  // 36864

    hipLaunchKernelGGL(prep_kernel, dim3(1024 + 216), dim3(256), 0, stream,
                       x, w_off, w_mask, w_dcn, xTb, wOffB, wMainB);
    hipLaunchKernelGGL(dcn_fused_kernel, dim3(1024), dim3(512), 0, stream,
                       xTb, wOffB, wMainB, b_off, b_mask, b_dcn, out);
}